// Round 1
// baseline (5668.708 us; speedup 1.0000x reference)
//
#include <hip/hip_runtime.h>
#include <cstdint>
#include <cstddef>

#define EMB    512
#define HID    512
#define NCLASS 50257
#define BATCH  64
#define STEPS  256
#define FOURH  2048

typedef __attribute__((ext_vector_type(8))) short    bf16x8;
typedef __attribute__((ext_vector_type(4))) float    f32x4;
typedef __attribute__((ext_vector_type(2))) _Float16 half2v;
typedef __attribute__((ext_vector_type(4))) _Float16 half4v;

__device__ __forceinline__ unsigned short f2bf(float f) {
    union { float f; unsigned int u; } v; v.f = f;
    unsigned int u = v.u;
    return (unsigned short)((u + 0x7fffu + ((u >> 16) & 1u)) >> 16);
}

// ---------------- prep kernels ----------------

__global__ void k_bias(const float* __restrict__ bi, const float* __restrict__ bh,
                       float* __restrict__ bias) {
    int i = blockIdx.x * 256 + threadIdx.x;
    if (i < FOURH) bias[i] = bi[i] + bh[i];
}

// Wi [512][2048] fp32 -> WiT [2048][512] bf16  (B^T layout for MFMA B-frags)
__global__ void k_wit(const float* __restrict__ Wi, unsigned short* __restrict__ WiT) {
    int n = blockIdx.x;        // 0..2047
    int l = threadIdx.x;       // 0..63
    int k0 = l * 8;
    unsigned short t[8];
#pragma unroll
    for (int i = 0; i < 8; i++)
        t[i] = f2bf(Wi[(size_t)(k0 + i) * FOURH + n]);
    uint4 v;
    v.x = (unsigned)t[0] | ((unsigned)t[1] << 16);
    v.y = (unsigned)t[2] | ((unsigned)t[3] << 16);
    v.z = (unsigned)t[4] | ((unsigned)t[5] << 16);
    v.w = (unsigned)t[6] | ((unsigned)t[7] << 16);
    *(uint4*)(WiT + (size_t)n * EMB + k0) = v;
}

// Wh [512][2048] fp32 -> fp16 (same layout). 262144 float4's.
__global__ void k_wh16(const float* __restrict__ Wh, _Float16* __restrict__ Wh16) {
    int i = blockIdx.x * 256 + threadIdx.x;   // 0..262143
    float4 v = ((const float4*)Wh)[i];
    half4v r = { (_Float16)v.x, (_Float16)v.y, (_Float16)v.z, (_Float16)v.w };
    ((half4v*)Wh16)[i] = r;
}

// XA[m][k] = bf16(emb[X[b][t]][k]),  m = t*64 + b
__global__ void k_gather(const int* __restrict__ X, const float* __restrict__ emb,
                         unsigned short* __restrict__ XA) {
    int chunk = blockIdx.x * 256 + threadIdx.x;  // 0..1048575 (8 elems each)
    int m  = chunk >> 6;
    int c8 = (chunk & 63) * 8;
    int t = m >> 6, b = m & 63;
    int row = X[b * STEPS + t];
    const float4* src = (const float4*)(emb + (size_t)row * EMB + c8);
    float4 f0 = src[0], f1 = src[1];
    uint4 v;
    v.x = (unsigned)f2bf(f0.x) | ((unsigned)f2bf(f0.y) << 16);
    v.y = (unsigned)f2bf(f0.z) | ((unsigned)f2bf(f0.w) << 16);
    v.z = (unsigned)f2bf(f1.x) | ((unsigned)f2bf(f1.y) << 16);
    v.w = (unsigned)f2bf(f1.z) | ((unsigned)f2bf(f1.w) << 16);
    *(uint4*)(XA + (size_t)m * EMB + c8) = v;
}

// ---------------- K1: XW = XA @ Wi + (bi+bh), bf16 MFMA ----------------
// 64x64 tile/block, 256 thr (4 waves), K-step 32, 16 steps.
// LDS row stride 48 halfwords (96B: 16B-aligned b128, ~4-way bank aliasing).
__global__ __launch_bounds__(256) void k_gemm1(const unsigned short* __restrict__ XA,
                                               const unsigned short* __restrict__ WiT,
                                               const float* __restrict__ bias,
                                               float* __restrict__ XW) {
    __shared__ unsigned short Al[64 * 48];
    __shared__ unsigned short Bl[64 * 48];
    const int m0 = blockIdx.y * 64;
    const int n0 = blockIdx.x * 64;
    const int tid  = threadIdx.x;
    const int w    = tid >> 6;
    const int lane = tid & 63;
    const int quad = lane >> 4;
    const int l16  = lane & 15;
    const int ar = tid >> 2;            // staging row 0..63
    const int ac = (tid & 3) * 8;       // staging col offset 0..24

    f32x4 acc[4];
#pragma unroll
    for (int i = 0; i < 4; i++) acc[i] = (f32x4){0.f, 0.f, 0.f, 0.f};

    for (int kk = 0; kk < 16; kk++) {
        const int k0 = kk * 32;
        __syncthreads();
        *(uint4*)(&Al[ar * 48 + ac]) = *(const uint4*)(XA  + (size_t)(m0 + ar) * EMB + k0 + ac);
        *(uint4*)(&Bl[ar * 48 + ac]) = *(const uint4*)(WiT + (size_t)(n0 + ar) * EMB + k0 + ac);
        __syncthreads();
        bf16x8 afrag = *(const bf16x8*)(&Al[(w * 16 + l16) * 48 + quad * 8]);
#pragma unroll
        for (int nt = 0; nt < 4; nt++) {
            bf16x8 bfrag = *(const bf16x8*)(&Bl[(nt * 16 + l16) * 48 + quad * 8]);
            acc[nt] = __builtin_amdgcn_mfma_f32_16x16x32_bf16(afrag, bfrag, acc[nt], 0, 0, 0);
        }
    }
    const int mrow = m0 + w * 16 + quad * 4;
#pragma unroll
    for (int nt = 0; nt < 4; nt++) {
        int n = n0 + nt * 16 + l16;
        float bv = bias[n];
#pragma unroll
        for (int r = 0; r < 4; r++)
            XW[(size_t)(mrow + r) * FOURH + n] = acc[nt][r] + bv;
    }
}

// ---------------- K2: sequential LSTM recurrence ----------------
// One block per batch element; 1024 threads, each owns cols {2*tid, 2*tid+1}.
// Wh in fp16 (2 MB, L2-resident), h state in LDS fp32, c in registers.
__global__ __launch_bounds__(1024) void k_rec(const float* __restrict__ XW,
                                              const _Float16* __restrict__ Wh16,
                                              float* __restrict__ hfinal) {
    __shared__ float hl[HID];
    __shared__ float pre[FOURH];
    const int b = blockIdx.x;
    const int tid = threadIdx.x;
    float creg = 0.f;
    float hreg = 0.f;
    if (tid < HID) hl[tid] = 0.f;
    __syncthreads();
    const half2v* Wh2 = (const half2v*)Wh16;   // [j][tid] pair of cols

    for (int t = 0; t < STEPS; t++) {
        const float2* xw2 = (const float2*)(XW + (size_t)(t * BATCH + b) * FOURH);
        float2 xv = xw2[tid];
        float a0 = xv.x, a1 = xv.y;
#pragma unroll 8
        for (int j = 0; j < HID; j++) {
            float hj = hl[j];
            half2v wv = Wh2[j * (FOURH / 2) + tid];
            a0 = fmaf(hj, (float)wv.x, a0);
            a1 = fmaf(hj, (float)wv.y, a1);
        }
        ((float2*)pre)[tid] = make_float2(a0, a1);
        __syncthreads();
        if (tid < HID) {
            float iv = pre[tid];
            float fv = pre[HID + tid];
            float gv = pre[2 * HID + tid];
            float ov = pre[3 * HID + tid];
            float is = 1.f / (1.f + __expf(-iv));
            float fs = 1.f / (1.f + __expf(-fv));
            float gt = tanhf(gv);
            float os = 1.f / (1.f + __expf(-ov));
            creg = fs * creg + is * gt;
            hreg = os * tanhf(creg);
            hl[tid] = hreg;
        }
        __syncthreads();
    }
    if (tid < HID) hfinal[b * HID + tid] = hreg;
}

// ---------------- K3: out = h @ Wout^T + bout ----------------
// 128 thr/block, 1 class-row per thread; h staged in LDS in 4 k-quarters.
__global__ __launch_bounds__(128) void k_out(const float* __restrict__ Wout,
                                             const float* __restrict__ bout,
                                             const float* __restrict__ hfinal,
                                             float* __restrict__ out) {
    __shared__ float hl[BATCH * 128];            // 32 KB: [b][128] quarter
    const int tid = threadIdx.x;
    const int n = blockIdx.x * 128 + tid;
    const bool valid = n < NCLASS;
    float acc[BATCH];
#pragma unroll
    for (int b = 0; b < BATCH; b++) acc[b] = 0.f;
    const float4* W4 = (const float4*)Wout;      // row = 128 float4
    const float4* h4 = (const float4*)hfinal;    // row = 128 float4
    float4* hl4 = (float4*)hl;

    for (int kq = 0; kq < 4; kq++) {
        __syncthreads();
#pragma unroll
        for (int i = 0; i < 16; i++) {
            int f = i * 128 + tid;               // 0..2047
            int b = f >> 5, kk = f & 31;
            hl4[f] = h4[b * 128 + kq * 32 + kk];
        }
        __syncthreads();
        if (valid) {
            for (int kk = 0; kk < 32; kk++) {
                float4 wv = W4[(size_t)n * 128 + kq * 32 + kk];
#pragma unroll
                for (int b = 0; b < BATCH; b++) {
                    float4 hv = hl4[b * 32 + kk];
                    acc[b] = fmaf(wv.x, hv.x, acc[b]);
                    acc[b] = fmaf(wv.y, hv.y, acc[b]);
                    acc[b] = fmaf(wv.z, hv.z, acc[b]);
                    acc[b] = fmaf(wv.w, hv.w, acc[b]);
                }
            }
        }
    }
    if (valid) {
        float bv = bout[n];
        for (int b = 0; b < BATCH; b++)
            out[(size_t)b * NCLASS + n] = acc[b] + bv;
    }
}

// ---------------- launch ----------------

extern "C" void kernel_launch(void* const* d_in, const int* in_sizes, int n_in,
                              void* d_out, int out_size, void* d_ws, size_t ws_size,
                              hipStream_t stream) {
    const int*   X    = (const int*)  d_in[0];
    const float* emb  = (const float*)d_in[1];
    const float* Wi   = (const float*)d_in[2];
    const float* Wh   = (const float*)d_in[3];
    const float* bi   = (const float*)d_in[4];
    const float* bh   = (const float*)d_in[5];
    // d_in[6..9]: layer-2 weights — dead code w.r.t. the output, skipped.
    const float* Wout = (const float*)d_in[10];
    const float* bout = (const float*)d_in[11];
    float* out = (float*)d_out;

    char* w = (char*)d_ws;
    float*          XW     = (float*)(w);                           // 134217728 B
    unsigned short* XA     = (unsigned short*)(w + 134217728);      //  16777216 B
    unsigned short* WiT    = (unsigned short*)(w + 150994944);      //   2097152 B
    _Float16*       Wh16   = (_Float16*)(w + 153092096);            //   2097152 B
    float*          bias   = (float*)(w + 155189248);               //      8192 B
    float*          hfinal = (float*)(w + 155197440);               //    131072 B
    // total 155328512 B (~148 MiB) of ws

    k_bias  <<<8,    256, 0, stream>>>(bi, bh, bias);
    k_wit   <<<2048,  64, 0, stream>>>(Wi, WiT);
    k_wh16  <<<1024, 256, 0, stream>>>(Wh, Wh16);
    k_gather<<<4096, 256, 0, stream>>>(X, emb, XA);
    k_gemm1 <<<dim3(32, 256), 256, 0, stream>>>(XA, WiT, bias, XW);
    k_rec   <<<64,  1024, 0, stream>>>(XW, Wh16, hfinal);
    k_out   <<<393,  128, 0, stream>>>(Wout, bout, hfinal, out);
}